// Round 1
// baseline (29699.908 us; speedup 1.0000x reference)
//
#include <hip/hip_runtime.h>
#include <math.h>

#define Bq   32
#define Sq   1024
#define Hq   256

#define NBLK 256
#define NTHR 512
#define GRP  16     // blocks per group (group owns 2 batch rows)

// --- workspace layout (bytes) ---
#define WS_CNT   0        // 16 group counters, 128-B spacing
#define WS_CELL  2048     // u64 cell[2][32]  (packed argmax, double-buffered)
#define WS_HBUF  4096     // f32 hbuf[2][32][256] (h state, double-buffered)
#define WS_TOTAL 69632

// --- LDS layout (float offsets) ---
#define L_W      0              // [128][260]  W slice (8 rows per k: 4 gates x {ih,hh}), padded
#define L_VX     33280          // [2][256]  x vectors (gathered enc rows)
#define L_VH     33792          // [2][256]  h_prev vectors
#define L_SCRA   34304          // [256][17] gemv partials (pitch 17 = conflict-free)
#define L_RSUM   38656          // [128][2]  row-dot sums
#define L_GVL    38912          // [2][16][4] gate values
#define L_BIASQ  39040          // [16][4]   b_ih+b_hh per (k_local, gate)
#define L_C      39104          // [2][16]   cell state (persistent)
#define L_MI     39136          // int[2]    gathered argmax indices
#define L_SCRB   39168          // [2][4][64] score partials
#define L_RED    39680          // [32]      softmax reduce scratch
#define L_FLOATS 39712
#define SMEM_BYTES (L_FLOATS*4)

__global__ void init_ws(unsigned int* ws) {
  int n = WS_TOTAL / 4;
  for (int i = threadIdx.x + blockIdx.x * blockDim.x; i < n; i += blockDim.x * gridDim.x)
    ws[i] = 0u;
}

__device__ __forceinline__ void group_barrier(unsigned int* mycnt) {
  __syncthreads();
  if (threadIdx.x == 0) {
    __threadfence();  // release: flush our h/score writes device-wide
    unsigned int old = __hip_atomic_fetch_add(mycnt, 1u, __ATOMIC_RELAXED, __HIP_MEMORY_SCOPE_AGENT);
    unsigned int tgt = (old / GRP + 1u) * GRP;
    while (__hip_atomic_load(mycnt, __ATOMIC_RELAXED, __HIP_MEMORY_SCOPE_AGENT) < tgt)
      __builtin_amdgcn_s_sleep(1);
    __threadfence();  // acquire: invalidate L1/L2 so we see peers' writes
  }
  __syncthreads();
}

__global__ void __launch_bounds__(NTHR, 2)
decoder_main(const float* __restrict__ enc, const float* __restrict__ wih,
             const float* __restrict__ whh, const float* __restrict__ bih,
             const float* __restrict__ bhh, float* __restrict__ out,
             unsigned char* wsb)
{
  extern __shared__ float sm[];
  unsigned int* cnt = (unsigned int*)(wsb + WS_CNT);
  unsigned long long* cell = (unsigned long long*)(wsb + WS_CELL);
  float* hbuf = (float*)(wsb + WS_HBUF);

  const int tid = threadIdx.x;
  const int grp = blockIdx.x & 15;   // group id (consecutive-ish XCD-wise for r via >>4)
  const int r   = blockIdx.x >> 4;   // rank within group, 0..15
  const int b0  = grp * 2;
  unsigned int* mycnt = cnt + grp * 32;

  // ---------------- init: W slice -> LDS ----------------
  // row = kl*8 + gate*2 + mat ; k = r*16+kl ; global W row = gate*256 + k
  for (int idx = tid; idx < 128 * 64; idx += NTHR) {
    int row = idx >> 6, c4 = idx & 63;
    int kl = row >> 3, gate = (row >> 1) & 3, mat = row & 1;
    const float* src = (mat ? whh : wih) + (size_t)(gate * Hq + r * 16 + kl) * Hq + c4 * 4;
    float4 v = *(const float4*)src;
    *(float4*)&sm[L_W + row * 260 + c4 * 4] = v;
  }
  if (tid < 64) {
    int kl = tid >> 2, gate = tid & 3;
    int gr = gate * Hq + r * 16 + kl;
    sm[L_BIASQ + kl * 4 + gate] = bih[gr] + bhh[gr];
  }
  if (tid < 32) sm[L_C + tid] = 0.f;

  // ---------------- init: enc slice -> registers ----------------
  // wave w = (b_loc, jc); lane = s_local. er[u] = enc[b0+bl][r*64+lane][jc*64+u]
  const int wid = tid >> 6, lane = tid & 63;
  const int bl = wid >> 2, jc = wid & 3;
  float er[64];
  {
    const float* ep = enc + ((size_t)(b0 + bl) * Sq + (size_t)(r * 64 + lane)) * Hq + jc * 64;
    #pragma unroll
    for (int u = 0; u < 16; ++u) {
      float4 v = *(const float4*)(ep + u * 4);
      er[u * 4 + 0] = v.x; er[u * 4 + 1] = v.y; er[u * 4 + 2] = v.z; er[u * 4 + 3] = v.w;
    }
  }
  __syncthreads();

  // ================= main recurrence =================
  for (int t = 0; t < Sq; ++t) {
    const int par = t & 1, prv = par ^ 1;

    // --- stage: read argmax idx, reset this step's cells ---
    if (tid < 2) {
      int ix = 0;
      if (t > 0) {
        unsigned long long cv = __hip_atomic_load(&cell[prv * 32 + b0 + tid],
                                                  __ATOMIC_RELAXED, __HIP_MEMORY_SCOPE_AGENT);
        ix = 1023 - (int)(cv & 0xFFFFFFFFu);
      }
      ((int*)&sm[L_MI])[tid] = ix;
      if (r == 0)
        __hip_atomic_store(&cell[par * 32 + b0 + tid], 0ull,
                           __ATOMIC_RELAXED, __HIP_MEMORY_SCOPE_AGENT);
    }
    __syncthreads();
    // --- stage x (pointer gather) and h_prev into LDS ---
    {
      int b = tid >> 8, j = tid & 255;
      float xv = 0.f, hv = 0.f;
      if (t > 0) {
        int ix = ((int*)&sm[L_MI])[b];
        xv = enc[((size_t)(b0 + b) * Sq + (size_t)ix) * Hq + j];
        hv = hbuf[(size_t)(prv * 32 + b0 + b) * Hq + j];
      }
      sm[L_VX + b * 256 + j] = xv;
      sm[L_VH + b * 256 + j] = hv;
    }
    __syncthreads();

    // --- phase A: gates GEMV (256 threads; 8-row tiles x 16-col blocks) ---
    if (tid < 256) {
      const int g = tid >> 4;     // row tile [8g, 8g+8)
      const int jcc = tid & 15;   // 16-float j block
      float acc[16];
      #pragma unroll
      for (int q = 0; q < 16; ++q) acc[q] = 0.f;
      #pragma unroll
      for (int i = 0; i < 4; ++i) {
        const int jb = jcc * 16 + 4 * ((i + g) & 3);  // rotated chunk order (bank spread)
        float4 wv[8];
        #pragma unroll
        for (int rr = 0; rr < 8; ++rr)
          wv[rr] = *(const float4*)&sm[L_W + (8 * g + rr) * 260 + jb];
        #pragma unroll
        for (int b = 0; b < 2; ++b) {
          float4 xv = *(const float4*)&sm[L_VX + b * 256 + jb];
          float4 hv = *(const float4*)&sm[L_VH + b * 256 + jb];
          #pragma unroll
          for (int rr = 0; rr < 8; ++rr) {
            float4 vv = (rr & 1) ? hv : xv;   // mat: even=ih(x), odd=hh(h)
            acc[rr * 2 + b] += wv[rr].x * vv.x + wv[rr].y * vv.y
                             + wv[rr].z * vv.z + wv[rr].w * vv.w;
          }
        }
      }
      #pragma unroll
      for (int rr = 0; rr < 8; ++rr)
        #pragma unroll
        for (int b = 0; b < 2; ++b)
          sm[L_SCRA + ((8 * g + rr) * 2 + b) * 17 + jcc] = acc[rr * 2 + b];
    }
    __syncthreads();
    if (tid < 256) {   // reduce 16 partials per (row,b)
      int row = tid >> 1, b = tid & 1;
      const float* p = &sm[L_SCRA + (row * 2 + b) * 17];
      float s = 0.f;
      #pragma unroll
      for (int q = 0; q < 16; ++q) s += p[q];
      sm[L_RSUM + row * 2 + b] = s;
    }
    __syncthreads();
    if (tid < 128) {   // combine ih+hh rows + biases
      int kl = tid >> 3, gate = (tid >> 1) & 3, b = tid & 1;
      int row = kl * 8 + gate * 2;
      float gv = sm[L_RSUM + row * 2 + b] + sm[L_RSUM + (row + 1) * 2 + b]
               + sm[L_BIASQ + kl * 4 + gate];
      sm[L_GVL + (b * 16 + kl) * 4 + gate] = gv;
    }
    __syncthreads();
    if (tid < 32) {    // LSTM cell update; write h slice
      int b = tid >> 4, kl = tid & 15;
      const float* g4 = &sm[L_GVL + (b * 16 + kl) * 4];
      float gi = 1.f / (1.f + expf(-g4[0]));
      float gf = 1.f / (1.f + expf(-g4[1]));
      float gg = tanhf(g4[2]);
      float go = 1.f / (1.f + expf(-g4[3]));
      float c = gf * sm[L_C + b * 16 + kl] + gi * gg;
      sm[L_C + b * 16 + kl] = c;
      float h = go * tanhf(c);
      hbuf[(size_t)(par * 32 + b0 + b) * Hq + r * 16 + kl] = h;
    }
    group_barrier(mycnt);   // #1: h_t complete & visible; cells reset

    // --- phase B: scores via enc-in-registers + readlane h broadcast ---
    float hval = hbuf[(size_t)(par * 32 + b0 + bl) * Hq + jc * 64 + lane];
    int hbits = __float_as_int(hval);
    float p0 = 0.f, p1 = 0.f, p2 = 0.f, p3 = 0.f;
    #pragma unroll
    for (int u = 0; u < 64; u += 4) {
      p0 = fmaf(er[u + 0], __int_as_float(__builtin_amdgcn_readlane(hbits, u + 0)), p0);
      p1 = fmaf(er[u + 1], __int_as_float(__builtin_amdgcn_readlane(hbits, u + 1)), p1);
      p2 = fmaf(er[u + 2], __int_as_float(__builtin_amdgcn_readlane(hbits, u + 2)), p2);
      p3 = fmaf(er[u + 3], __int_as_float(__builtin_amdgcn_readlane(hbits, u + 3)), p3);
    }
    float ps = (p0 + p1) + (p2 + p3);
    sm[L_SCRB + (bl * 4 + jc) * 64 + lane] = ps;
    __syncthreads();
    if (tid < 128) {   // reduce jc partials; write score; wave-argmax; atomicMax
      int b = tid >> 6, sl = tid & 63;
      const float* q = &sm[L_SCRB + b * 256 + sl];
      float sc = (q[0] + q[64]) + (q[128] + q[192]);
      out[((size_t)(b0 + b) * Sq + (size_t)t) * Sq + r * 64 + sl] = sc;
      unsigned int kb = __float_as_uint(sc);
      kb = (kb & 0x80000000u) ? ~kb : (kb | 0x80000000u);   // sortable key
      unsigned long long pk = ((unsigned long long)kb << 32)
                            | (unsigned long long)(1023 - (r * 64 + sl)); // tie -> lowest s
      #pragma unroll
      for (int off = 32; off > 0; off >>= 1) {
        unsigned long long o = __shfl_down(pk, off);
        if (o > pk) pk = o;
      }
      if (sl == 0) atomicMax(&cell[par * 32 + b0 + b], pk);
    }
    group_barrier(mycnt);   // #2: argmax final & visible
  }

  // ================= deferred softmax (in-place on d_out) =================
  for (int u = 0; u < 128; ++u) {
    int rid = u * 16 + r;
    int b = rid >> 10, tt = rid & 1023;
    float* rowp = out + ((size_t)(b0 + b) * Sq + (size_t)tt) * Sq;
    float2 v = *(const float2*)(rowp + tid * 2);
    float m = fmaxf(v.x, v.y);
    #pragma unroll
    for (int off = 32; off; off >>= 1) m = fmaxf(m, __shfl_xor(m, off));
    if (lane == 0) sm[L_RED + wid] = m;
    __syncthreads();
    if (tid == 0) {
      float mm = sm[L_RED];
      #pragma unroll
      for (int w = 1; w < 8; ++w) mm = fmaxf(mm, sm[L_RED + w]);
      sm[L_RED + 16] = mm;
    }
    __syncthreads();
    float mx = sm[L_RED + 16];
    float e0 = __expf(v.x - mx), e1 = __expf(v.y - mx);
    float s = e0 + e1;
    #pragma unroll
    for (int off = 32; off; off >>= 1) s += __shfl_xor(s, off);
    if (lane == 0) sm[L_RED + wid] = s;
    __syncthreads();
    if (tid == 0) {
      float ss = 0.f;
      #pragma unroll
      for (int w = 0; w < 8; ++w) ss += sm[L_RED + w];
      sm[L_RED + 17] = 1.f / ss;
    }
    __syncthreads();
    float inv = sm[L_RED + 17];
    float2 o2; o2.x = e0 * inv; o2.y = e1 * inv;
    *(float2*)(rowp + tid * 2) = o2;
    __syncthreads();
  }
}

extern "C" void kernel_launch(void* const* d_in, const int* in_sizes, int n_in,
                              void* d_out, int out_size, void* d_ws, size_t ws_size,
                              hipStream_t stream) {
  const float* enc = (const float*)d_in[0];
  const float* wih = (const float*)d_in[1];
  const float* whh = (const float*)d_in[2];
  const float* bih = (const float*)d_in[3];
  const float* bhh = (const float*)d_in[4];
  float* outp = (float*)d_out;
  unsigned char* ws = (unsigned char*)d_ws;

  hipLaunchKernelGGL(init_ws, dim3(64), dim3(256), 0, stream, (unsigned int*)ws);

  hipFuncSetAttribute((const void*)decoder_main,
                      hipFuncAttributeMaxDynamicSharedMemorySize, SMEM_BYTES);

  void* args[] = { (void*)&enc, (void*)&wih, (void*)&whh, (void*)&bih,
                   (void*)&bhh, (void*)&outp, (void*)&ws };
  hipLaunchCooperativeKernel((void*)decoder_main, dim3(NBLK), dim3(NTHR),
                             args, SMEM_BYTES, stream);
}

// Round 2
// 7819.933 us; speedup vs baseline: 3.7980x; 3.7980x over previous
//
#include <hip/hip_runtime.h>
#include <math.h>

#define Bq   32
#define Sq   1024
#define Hq   256

#define NBLK 256
#define NTHR 512
#define GRP  16     // blocks per group (group owns 2 batch rows)

// --- workspace layout (bytes) ---
#define WS_CNT   0        // 16 group counters, 128-B spacing
#define WS_CELL  2048     // u64 cell[2][32]  (packed argmax, double-buffered)
#define WS_HBUF  4096     // f32 hbuf[2][32][256] (h state, double-buffered)
#define WS_TOTAL 69632

// --- LDS layout (float offsets) ---
#define L_W      0              // [128][260]  W slice (8 rows per k: 4 gates x {ih,hh}), padded
#define L_VX     33280          // [2][256]  x vectors (gathered enc rows)
#define L_VH     33792          // [2][256]  h_prev vectors
#define L_SCRA   34304          // [16][272] gemv partials, transposed: [jcc][g + 16*(2rr+b)]
#define L_RSUM   38656          // [128][2]  row-dot sums
#define L_GVL    38912          // [2][16][4] gate values
#define L_BIASQ  39040          // [16][4]   b_ih+b_hh per (k_local, gate)
#define L_C      39104          // [2][16]   cell state (persistent)
#define L_MI     39136          // int[2]    gathered argmax indices
#define L_SCRB   39168          // [2][4][64] score partials
#define L_RED    39680          // [32]      softmax reduce scratch
#define L_FLOATS 39712
#define SMEM_BYTES (L_FLOATS*4)

__global__ void init_ws(unsigned int* ws) {
  int n = WS_TOTAL / 4;
  for (int i = threadIdx.x + blockIdx.x * blockDim.x; i < n; i += blockDim.x * gridDim.x)
    ws[i] = 0u;
}

// Fence-free group barrier: NO __threadfence (agent fence = full L2 wb+inv on
// gfx950 — was ~75% of R1's runtime). All cross-block data uses cache-bypassing
// AGENT-scope atomics, so the only ordering needed is "my vmem ops are ack'd at
// the coherence point before my arrival is visible": per-wave s_waitcnt vmcnt(0)
// (all waves! wave1 issues the argmax RMW) + syncthreads, then tid0 inc+spin.
__device__ __forceinline__ void group_barrier(unsigned int* mycnt) {
  asm volatile("s_waitcnt vmcnt(0)" ::: "memory");
  __syncthreads();
  if (threadIdx.x == 0) {
    unsigned int old = __hip_atomic_fetch_add(mycnt, 1u, __ATOMIC_RELAXED, __HIP_MEMORY_SCOPE_AGENT);
    unsigned int tgt = (old / GRP + 1u) * GRP;
    while (__hip_atomic_load(mycnt, __ATOMIC_RELAXED, __HIP_MEMORY_SCOPE_AGENT) < tgt) {}
  }
  __syncthreads();
}

__global__ void __launch_bounds__(NTHR, 2)
decoder_main(const float* __restrict__ enc, const float* __restrict__ wih,
             const float* __restrict__ whh, const float* __restrict__ bih,
             const float* __restrict__ bhh, float* __restrict__ out,
             unsigned char* wsb)
{
  extern __shared__ float sm[];
  unsigned int* cnt = (unsigned int*)(wsb + WS_CNT);
  unsigned long long* cell = (unsigned long long*)(wsb + WS_CELL);
  float* hbuf = (float*)(wsb + WS_HBUF);

  const int tid = threadIdx.x;
  const int grp = blockIdx.x & 15;
  const int r   = blockIdx.x >> 4;   // rank within group, 0..15
  const int b0  = grp * 2;
  unsigned int* mycnt = cnt + grp * 32;

  // ---------------- init: W slice -> LDS ----------------
  // row = kl*8 + gate*2 + mat ; k = r*16+kl ; global W row = gate*256 + k
  for (int idx = tid; idx < 128 * 64; idx += NTHR) {
    int row = idx >> 6, c4 = idx & 63;
    int kl = row >> 3, gate = (row >> 1) & 3, mat = row & 1;
    const float* src = (mat ? whh : wih) + (size_t)(gate * Hq + r * 16 + kl) * Hq + c4 * 4;
    float4 v = *(const float4*)src;
    *(float4*)&sm[L_W + row * 260 + c4 * 4] = v;
  }
  if (tid < 64) {
    int kl = tid >> 2, gate = tid & 3;
    int gr = gate * Hq + r * 16 + kl;
    sm[L_BIASQ + kl * 4 + gate] = bih[gr] + bhh[gr];
  }
  if (tid < 32) sm[L_C + tid] = 0.f;

  // ---------------- init: enc slice -> registers ----------------
  const int wid = tid >> 6, lane = tid & 63;
  const int bl = wid >> 2, jc = wid & 3;
  float er[64];
  {
    const float* ep = enc + ((size_t)(b0 + bl) * Sq + (size_t)(r * 64 + lane)) * Hq + jc * 64;
    #pragma unroll
    for (int u = 0; u < 16; ++u) {
      float4 v = *(const float4*)(ep + u * 4);
      er[u * 4 + 0] = v.x; er[u * 4 + 1] = v.y; er[u * 4 + 2] = v.z; er[u * 4 + 3] = v.w;
    }
  }
  __syncthreads();

  // ================= main recurrence =================
  for (int t = 0; t < Sq; ++t) {
    const int par = t & 1, prv = par ^ 1;

    // --- stage: read argmax idx, reset this step's cells ---
    if (tid < 2) {
      int ix = 0;
      if (t > 0) {
        unsigned long long cv = __hip_atomic_load(&cell[prv * 32 + b0 + tid],
                                                  __ATOMIC_RELAXED, __HIP_MEMORY_SCOPE_AGENT);
        ix = 1023 - (int)(cv & 0xFFFFFFFFu);
      }
      ((int*)&sm[L_MI])[tid] = ix;
      if (r == 0)
        __hip_atomic_store(&cell[par * 32 + b0 + tid], 0ull,
                           __ATOMIC_RELAXED, __HIP_MEMORY_SCOPE_AGENT);
    }
    __syncthreads();
    // --- stage x (pointer gather) and h_prev into LDS ---
    {
      int b = tid >> 8, j = tid & 255;
      float xv = 0.f, hv = 0.f;
      if (t > 0) {
        int ix = ((int*)&sm[L_MI])[b];
        xv = enc[((size_t)(b0 + b) * Sq + (size_t)ix) * Hq + j];
        hv = __hip_atomic_load(&hbuf[(size_t)(prv * 32 + b0 + b) * Hq + j],
                               __ATOMIC_RELAXED, __HIP_MEMORY_SCOPE_AGENT);
      }
      sm[L_VX + b * 256 + j] = xv;
      sm[L_VH + b * 256 + j] = hv;
    }
    __syncthreads();

    // --- phase A: gates GEMV. Mapping: g = tid&15 (row tile), jcc = tid>>4
    // (j block). Serving groups of 8 lanes differ in g -> (i+g)&3 rotation
    // spreads them over 4 float4 start-banks -> <=2-way (free). ---
    if (tid < 256) {
      const int g = tid & 15;     // row tile [8g, 8g+8)
      const int jcc = tid >> 4;   // 16-float j block
      float acc[16];
      #pragma unroll
      for (int q = 0; q < 16; ++q) acc[q] = 0.f;
      #pragma unroll
      for (int i = 0; i < 4; ++i) {
        const int jb = jcc * 16 + 4 * ((i + g) & 3);  // rotated chunk order
        float4 wv[8];
        #pragma unroll
        for (int rr = 0; rr < 8; ++rr)
          wv[rr] = *(const float4*)&sm[L_W + (8 * g + rr) * 260 + jb];
        #pragma unroll
        for (int b = 0; b < 2; ++b) {
          float4 xv = *(const float4*)&sm[L_VX + b * 256 + jb];
          float4 hv = *(const float4*)&sm[L_VH + b * 256 + jb];
          #pragma unroll
          for (int rr = 0; rr < 8; ++rr) {
            float4 vv = (rr & 1) ? hv : xv;   // even=ih(x), odd=hh(h)
            acc[rr * 2 + b] += wv[rr].x * vv.x + wv[rr].y * vv.y
                             + wv[rr].z * vv.z + wv[rr].w * vv.w;
          }
        }
      }
      // transposed partial store: [jcc][g + 16*(2rr+b)], pitch 272
      #pragma unroll
      for (int rr = 0; rr < 8; ++rr)
        #pragma unroll
        for (int b = 0; b < 2; ++b)
          sm[L_SCRA + jcc * 272 + (g + 16 * (rr * 2 + b))] = acc[rr * 2 + b];
    }
    __syncthreads();
    if (tid < 256) {   // reduce 16 jcc-partials per (row,b); reads stride-272: 2-way
      int g2 = tid & 15, rrb = tid >> 4;
      int rr2 = rrb >> 1, b2 = rrb & 1;
      float s = 0.f;
      #pragma unroll
      for (int q = 0; q < 16; ++q) s += sm[L_SCRA + q * 272 + tid];
      sm[L_RSUM + ((8 * g2 + rr2) * 2 + b2)] = s;
    }
    __syncthreads();
    if (tid < 128) {   // combine ih+hh rows + biases
      int kl = tid >> 3, gate = (tid >> 1) & 3, b = tid & 1;
      int row = kl * 8 + gate * 2;
      float gv = sm[L_RSUM + row * 2 + b] + sm[L_RSUM + (row + 1) * 2 + b]
               + sm[L_BIASQ + kl * 4 + gate];
      sm[L_GVL + (b * 16 + kl) * 4 + gate] = gv;
    }
    __syncthreads();
    if (tid < 32) {    // LSTM cell update; write h slice (agent atomics, wave 0)
      int b = tid >> 4, kl = tid & 15;
      const float* g4 = &sm[L_GVL + (b * 16 + kl) * 4];
      float gi = 1.f / (1.f + expf(-g4[0]));
      float gf = 1.f / (1.f + expf(-g4[1]));
      float gg = tanhf(g4[2]);
      float go = 1.f / (1.f + expf(-g4[3]));
      float c = gf * sm[L_C + b * 16 + kl] + gi * gg;
      sm[L_C + b * 16 + kl] = c;
      float h = go * tanhf(c);
      __hip_atomic_store(&hbuf[(size_t)(par * 32 + b0 + b) * Hq + r * 16 + kl], h,
                         __ATOMIC_RELAXED, __HIP_MEMORY_SCOPE_AGENT);
    }
    group_barrier(mycnt);   // #1: h_t complete & visible; cells reset

    // --- phase B: scores via enc-in-registers + readlane h broadcast ---
    float hval = __hip_atomic_load(&hbuf[(size_t)(par * 32 + b0 + bl) * Hq + jc * 64 + lane],
                                   __ATOMIC_RELAXED, __HIP_MEMORY_SCOPE_AGENT);
    int hbits = __float_as_int(hval);
    float p0 = 0.f, p1 = 0.f, p2 = 0.f, p3 = 0.f;
    #pragma unroll
    for (int u = 0; u < 64; u += 4) {
      p0 = fmaf(er[u + 0], __int_as_float(__builtin_amdgcn_readlane(hbits, u + 0)), p0);
      p1 = fmaf(er[u + 1], __int_as_float(__builtin_amdgcn_readlane(hbits, u + 1)), p1);
      p2 = fmaf(er[u + 2], __int_as_float(__builtin_amdgcn_readlane(hbits, u + 2)), p2);
      p3 = fmaf(er[u + 3], __int_as_float(__builtin_amdgcn_readlane(hbits, u + 3)), p3);
    }
    float ps = (p0 + p1) + (p2 + p3);
    sm[L_SCRB + (bl * 4 + jc) * 64 + lane] = ps;
    __syncthreads();
    if (tid < 128) {   // reduce jc partials; write score; wave-argmax; atomicMax
      int b = tid >> 6, sl = tid & 63;
      const float* q = &sm[L_SCRB + b * 256 + sl];
      float sc = (q[0] + q[64]) + (q[128] + q[192]);
      out[((size_t)(b0 + b) * Sq + (size_t)t) * Sq + r * 64 + sl] = sc;  // plain, flushed once at end
      unsigned int kb = __float_as_uint(sc);
      kb = (kb & 0x80000000u) ? ~kb : (kb | 0x80000000u);   // sortable key
      unsigned long long pk = ((unsigned long long)kb << 32)
                            | (unsigned long long)(1023 - (r * 64 + sl)); // tie -> lowest s
      #pragma unroll
      for (int off = 32; off > 0; off >>= 1) {
        unsigned long long o = __shfl_down(pk, off);
        if (o > pk) pk = o;
      }
      if (sl == 0) atomicMax(&cell[par * 32 + b0 + b], pk);
    }
    group_barrier(mycnt);   // #2: argmax final & visible
  }

  // One-time flush of cached score writes (wbl2+inv), then group barrier so
  // peers' rows are at the coherence point before we read them.
  __threadfence();
  group_barrier(mycnt);

  // ================= deferred softmax (in-place on d_out) =================
  for (int u = 0; u < 128; ++u) {
    int rid = u * 16 + r;
    int b = rid >> 10, tt = rid & 1023;
    float* rowp = out + ((size_t)(b0 + b) * Sq + (size_t)tt) * Sq;
    float2 v = *(const float2*)(rowp + tid * 2);
    float m = fmaxf(v.x, v.y);
    #pragma unroll
    for (int off = 32; off; off >>= 1) m = fmaxf(m, __shfl_xor(m, off));
    if (lane == 0) sm[L_RED + wid] = m;
    __syncthreads();
    if (tid == 0) {
      float mm = sm[L_RED];
      #pragma unroll
      for (int w = 1; w < 8; ++w) mm = fmaxf(mm, sm[L_RED + w]);
      sm[L_RED + 16] = mm;
    }
    __syncthreads();
    float mx = sm[L_RED + 16];
    float e0 = __expf(v.x - mx), e1 = __expf(v.y - mx);
    float s = e0 + e1;
    #pragma unroll
    for (int off = 32; off; off >>= 1) s += __shfl_xor(s, off);
    if (lane == 0) sm[L_RED + wid] = s;
    __syncthreads();
    if (tid == 0) {
      float ss = 0.f;
      #pragma unroll
      for (int w = 0; w < 8; ++w) ss += sm[L_RED + w];
      sm[L_RED + 17] = 1.f / ss;
    }
    __syncthreads();
    float inv = sm[L_RED + 17];
    float2 o2; o2.x = e0 * inv; o2.y = e1 * inv;
    *(float2*)(rowp + tid * 2) = o2;
    __syncthreads();
  }
}

extern "C" void kernel_launch(void* const* d_in, const int* in_sizes, int n_in,
                              void* d_out, int out_size, void* d_ws, size_t ws_size,
                              hipStream_t stream) {
  const float* enc = (const float*)d_in[0];
  const float* wih = (const float*)d_in[1];
  const float* whh = (const float*)d_in[2];
  const float* bih = (const float*)d_in[3];
  const float* bhh = (const float*)d_in[4];
  float* outp = (float*)d_out;
  unsigned char* ws = (unsigned char*)d_ws;

  hipLaunchKernelGGL(init_ws, dim3(64), dim3(256), 0, stream, (unsigned int*)ws);

  hipFuncSetAttribute((const void*)decoder_main,
                      hipFuncAttributeMaxDynamicSharedMemorySize, SMEM_BYTES);

  void* args[] = { (void*)&enc, (void*)&wih, (void*)&whh, (void*)&bih,
                   (void*)&bhh, (void*)&outp, (void*)&ws };
  hipLaunchCooperativeKernel((void*)decoder_main, dim3(NBLK), dim3(NTHR),
                             args, SMEM_BYTES, stream);
}

// Round 3
// 5661.201 us; speedup vs baseline: 5.2462x; 1.3813x over previous
//
#include <hip/hip_runtime.h>
#include <math.h>

#define Bq   32
#define Sq   1024
#define Hq   256

#define NBLK 256
#define NTHR 512
#define GRP  16     // blocks per group (group owns 2 batch rows)

// --- workspace layout (bytes) ---
#define WS_CNT   0        // 16 group counters, 128-B spacing
#define WS_CELL  2048     // u64 cell[2][32]  (packed argmax, double-buffered)
#define WS_HBUF  4096     // f32 hbuf[2][32][256] (h state, double-buffered)
#define WS_TOTAL 69632

// --- LDS layout (float offsets) --- (~12 KB used; SMEM padded to force 1 blk/CU)
#define L_VX     0        // [2][256]  x vectors
#define L_VH     512      // [2][256]  h_prev vectors (stashed by phase B)
#define L_SCR    1024     // [128][9]  gemv partials: (mat*64+l64)*9 + q*2 + b
#define L_GVL    2176     // [2][64]   gate values: b*64 + kl*4 + gate
#define L_BIAS   2304     // [64]      b_ih+b_hh, flattened kl*4+gate
#define L_C      2368     // [2][16]   cell state (persistent)
#define L_SCRB   2400     // [8][64]   score partials
#define SMEM_BYTES (84*1024)   // > 160K/2: pins exactly 1 block per CU

__global__ void init_ws(unsigned int* ws) {
  int n = WS_TOTAL / 4;
  for (int i = threadIdx.x + blockIdx.x * blockDim.x; i < n; i += blockDim.x * gridDim.x)
    ws[i] = 0u;
}

// Fence-free group barrier (R2, proven): per-wave vmcnt(0) drain so all vmem
// (h stores, argmax RMW, cell resets) is at the coherence point, then counter.
__device__ __forceinline__ void group_barrier(unsigned int* mycnt) {
  asm volatile("s_waitcnt vmcnt(0)" ::: "memory");
  __syncthreads();
  if (threadIdx.x == 0) {
    unsigned int old = __hip_atomic_fetch_add(mycnt, 1u, __ATOMIC_RELAXED, __HIP_MEMORY_SCOPE_AGENT);
    unsigned int tgt = (old / GRP + 1u) * GRP;
    while (__hip_atomic_load(mycnt, __ATOMIC_RELAXED, __HIP_MEMORY_SCOPE_AGENT) < tgt) {}
  }
  __syncthreads();
}

__global__ void __launch_bounds__(NTHR, 2)
decoder_main(const float* __restrict__ enc, const float* __restrict__ wih,
             const float* __restrict__ whh, const float* __restrict__ bih,
             const float* __restrict__ bhh, float* __restrict__ out,
             unsigned char* wsb)
{
  extern __shared__ float sm[];
  unsigned int* cnt = (unsigned int*)(wsb + WS_CNT);
  unsigned long long* cell = (unsigned long long*)(wsb + WS_CELL);
  float* hbuf = (float*)(wsb + WS_HBUF);

  const int tid = threadIdx.x;
  const int grp = blockIdx.x & 15;
  const int r   = blockIdx.x >> 4;   // rank within group, 0..15
  const int b0  = grp * 2;
  unsigned int* mycnt = cnt + grp * 32;

  const int wid = tid >> 6, lane = tid & 63;
  // phase-A roles: wave -> (mat, col-quarter); lane -> W row l64 = kl*4+gate
  const int amat = wid >> 2, aq = wid & 3;
  const int kl_a = lane >> 2, gate_a = lane & 3;
  // phase-B roles: wave -> (batch-local, col-quarter); lane -> s_local
  const int bbl = wid >> 2, bjc = wid & 3;

  // ---------------- init: W slice -> REGISTERS (64 floats/thread) ----------------
  float wreg[64];
  {
    const float* wsrc = (amat ? whh : wih)
                      + ((size_t)(gate_a * Hq + r * 16 + kl_a)) * Hq + aq * 64;
    #pragma unroll
    for (int u = 0; u < 16; ++u) {
      float4 v = *(const float4*)(wsrc + u * 4);
      wreg[u * 4 + 0] = v.x; wreg[u * 4 + 1] = v.y;
      wreg[u * 4 + 2] = v.z; wreg[u * 4 + 3] = v.w;
    }
  }
  // ---------------- init: enc slice -> registers ----------------
  float er[64];
  {
    const float* ep = enc + ((size_t)(b0 + bbl) * Sq + (size_t)(r * 64 + lane)) * Hq + bjc * 64;
    #pragma unroll
    for (int u = 0; u < 16; ++u) {
      float4 v = *(const float4*)(ep + u * 4);
      er[u * 4 + 0] = v.x; er[u * 4 + 1] = v.y;
      er[u * 4 + 2] = v.z; er[u * 4 + 3] = v.w;
    }
  }
  // ---------------- init: LDS ----------------
  for (int i = tid; i < 1024; i += NTHR) sm[L_VX + i] = 0.f;  // zeros VX+VH
  if (tid < 64) {
    int gr = gate_a * Hq + r * 16 + kl_a;  // tid<64 -> lane==tid
    sm[L_BIAS + tid] = bih[gr] + bhh[gr];
  }
  if (tid < 32) sm[L_C + tid] = 0.f;
  __syncthreads();

  // ================= main recurrence =================
  for (int t = 0; t < Sq; ++t) {
    const int par = t & 1, prv = par ^ 1;

    // --- stage: read prev argmax directly, gather x; reset this step's cells ---
    if (t > 0) {
      int b = tid >> 8, j = tid & 255;
      unsigned long long cv = __hip_atomic_load(&cell[prv * 32 + b0 + b],
                                                __ATOMIC_RELAXED, __HIP_MEMORY_SCOPE_AGENT);
      int ix = 1023 - (int)(cv & 0xFFFFFFFFu);
      sm[L_VX + b * 256 + j] = enc[((size_t)(b0 + b) * Sq + (size_t)ix) * Hq + j];
    }
    if (r == 0 && (tid & 255) == 0)
      __hip_atomic_store(&cell[par * 32 + b0 + (tid >> 8)], 0ull,
                         __ATOMIC_RELAXED, __HIP_MEMORY_SCOPE_AGENT);
    __syncthreads();   // VX ready (VH stashed by prev phase B / pre-zeroed)

    // --- phase A: dual GEMV, W in registers, v broadcast via readlane ---
    {
      const int vbase = (amat ? L_VH : L_VX) + aq * 64 + lane;
      int vb0 = __float_as_int(sm[vbase]);
      int vb1 = __float_as_int(sm[vbase + 256]);
      float a0 = 0.f, a1 = 0.f;
      #pragma unroll
      for (int u = 0; u < 64; ++u) {
        float s0 = __int_as_float(__builtin_amdgcn_readlane(vb0, u));
        float s1 = __int_as_float(__builtin_amdgcn_readlane(vb1, u));
        a0 = fmaf(wreg[u], s0, a0);
        a1 = fmaf(wreg[u], s1, a1);
      }
      sm[L_SCR + (amat * 64 + lane) * 9 + aq * 2 + 0] = a0;
      sm[L_SCR + (amat * 64 + lane) * 9 + aq * 2 + 1] = a1;
    }
    __syncthreads();

    // --- combine quarters + ih/hh + bias -> gates ---
    if (tid < 128) {
      int b = tid >> 6, l64 = tid & 63;
      float s = sm[L_BIAS + l64];
      #pragma unroll
      for (int q = 0; q < 4; ++q) s += sm[L_SCR + l64 * 9 + q * 2 + b];
      #pragma unroll
      for (int q = 0; q < 4; ++q) s += sm[L_SCR + (64 + l64) * 9 + q * 2 + b];
      sm[L_GVL + b * 64 + l64] = s;
    }
    __syncthreads();

    // --- LSTM cell update; publish h slice ---
    if (tid < 32) {
      int b = tid >> 4, kl = tid & 15;
      float g0 = sm[L_GVL + b * 64 + kl * 4 + 0];
      float g1 = sm[L_GVL + b * 64 + kl * 4 + 1];
      float g2 = sm[L_GVL + b * 64 + kl * 4 + 2];
      float g3 = sm[L_GVL + b * 64 + kl * 4 + 3];
      float gi = 1.f / (1.f + expf(-g0));
      float gf = 1.f / (1.f + expf(-g1));
      float gg = tanhf(g2);
      float go = 1.f / (1.f + expf(-g3));
      float c = gf * sm[L_C + b * 16 + kl] + gi * gg;
      sm[L_C + b * 16 + kl] = c;
      float h = go * tanhf(c);
      __hip_atomic_store(&hbuf[(size_t)(par * 32 + b0 + b) * Hq + r * 16 + kl], h,
                         __ATOMIC_RELAXED, __HIP_MEMORY_SCOPE_AGENT);
    }
    group_barrier(mycnt);   // #1: h_t complete & visible; cells reset

    // --- phase B: scores via enc-in-registers + readlane h broadcast ---
    {
      float hval = __hip_atomic_load(&hbuf[(size_t)(par * 32 + b0 + bbl) * Hq + bjc * 64 + lane],
                                     __ATOMIC_RELAXED, __HIP_MEMORY_SCOPE_AGENT);
      sm[L_VH + bbl * 256 + bjc * 64 + lane] = hval;   // stash for next step's phase A
      int hbits = __float_as_int(hval);
      float p0 = 0.f, p1 = 0.f, p2 = 0.f, p3 = 0.f;
      #pragma unroll
      for (int u = 0; u < 64; u += 4) {
        p0 = fmaf(er[u + 0], __int_as_float(__builtin_amdgcn_readlane(hbits, u + 0)), p0);
        p1 = fmaf(er[u + 1], __int_as_float(__builtin_amdgcn_readlane(hbits, u + 1)), p1);
        p2 = fmaf(er[u + 2], __int_as_float(__builtin_amdgcn_readlane(hbits, u + 2)), p2);
        p3 = fmaf(er[u + 3], __int_as_float(__builtin_amdgcn_readlane(hbits, u + 3)), p3);
      }
      float ps = (p0 + p1) + (p2 + p3);
      sm[L_SCRB + wid * 64 + lane] = ps;
    }
    __syncthreads();
    if (tid < 128) {   // reduce quarters; write score; wave-argmax; atomicMax
      int b = tid >> 6, sl = tid & 63;
      const float* q = &sm[L_SCRB + b * 256 + sl];
      float sc = (q[0] + q[64]) + (q[128] + q[192]);
      out[((size_t)(b0 + b) * Sq + (size_t)t) * Sq + r * 64 + sl] = sc;
      unsigned int kb = __float_as_uint(sc);
      kb = (kb & 0x80000000u) ? ~kb : (kb | 0x80000000u);   // sortable key
      unsigned long long pk = ((unsigned long long)kb << 32)
                            | (unsigned long long)(1023 - (r * 64 + sl)); // tie -> lowest s
      #pragma unroll
      for (int off = 32; off > 0; off >>= 1) {
        unsigned long long o = __shfl_down(pk, off);
        if (o > pk) pk = o;
      }
      if (sl == 0) atomicMax(&cell[par * 32 + b0 + b], pk);
    }
    group_barrier(mycnt);   // #2: argmax final & visible
  }

  // One-time flush+inv of cached score lines, then group barrier: peers' rows
  // are at the coherence point and our L2 holds nothing stale.
  __threadfence();
  group_barrier(mycnt);

  // ================= deferred softmax: one row per wave, no syncs =================
  {
    const int gw = r * 8 + wid;   // wave id within group, 0..127
    #pragma unroll 1
    for (int u = 0; u < 16; ++u) {
      int lr = u * 128 + gw;            // local row 0..2047
      int b = lr >> 10, tt = lr & 1023;
      float* rowp = out + ((size_t)(b0 + b) * Sq + (size_t)tt) * Sq;
      float4 x0 = *(const float4*)(rowp + lane * 16 + 0);
      float4 x1 = *(const float4*)(rowp + lane * 16 + 4);
      float4 x2 = *(const float4*)(rowp + lane * 16 + 8);
      float4 x3 = *(const float4*)(rowp + lane * 16 + 12);
      float m = fmaxf(fmaxf(fmaxf(x0.x, x0.y), fmaxf(x0.z, x0.w)),
                      fmaxf(fmaxf(x1.x, x1.y), fmaxf(x1.z, x1.w)));
      m = fmaxf(m, fmaxf(fmaxf(fmaxf(x2.x, x2.y), fmaxf(x2.z, x2.w)),
                         fmaxf(fmaxf(x3.x, x3.y), fmaxf(x3.z, x3.w))));
      #pragma unroll
      for (int off = 32; off; off >>= 1) m = fmaxf(m, __shfl_xor(m, off));
      x0.x = __expf(x0.x - m); x0.y = __expf(x0.y - m); x0.z = __expf(x0.z - m); x0.w = __expf(x0.w - m);
      x1.x = __expf(x1.x - m); x1.y = __expf(x1.y - m); x1.z = __expf(x1.z - m); x1.w = __expf(x1.w - m);
      x2.x = __expf(x2.x - m); x2.y = __expf(x2.y - m); x2.z = __expf(x2.z - m); x2.w = __expf(x2.w - m);
      x3.x = __expf(x3.x - m); x3.y = __expf(x3.y - m); x3.z = __expf(x3.z - m); x3.w = __expf(x3.w - m);
      float s = ((x0.x + x0.y) + (x0.z + x0.w)) + ((x1.x + x1.y) + (x1.z + x1.w))
              + ((x2.x + x2.y) + (x2.z + x2.w)) + ((x3.x + x3.y) + (x3.z + x3.w));
      #pragma unroll
      for (int off = 32; off; off >>= 1) s += __shfl_xor(s, off);
      float inv = 1.f / s;
      x0.x *= inv; x0.y *= inv; x0.z *= inv; x0.w *= inv;
      x1.x *= inv; x1.y *= inv; x1.z *= inv; x1.w *= inv;
      x2.x *= inv; x2.y *= inv; x2.z *= inv; x2.w *= inv;
      x3.x *= inv; x3.y *= inv; x3.z *= inv; x3.w *= inv;
      *(float4*)(rowp + lane * 16 + 0)  = x0;
      *(float4*)(rowp + lane * 16 + 4)  = x1;
      *(float4*)(rowp + lane * 16 + 8)  = x2;
      *(float4*)(rowp + lane * 16 + 12) = x3;
    }
  }
}

extern "C" void kernel_launch(void* const* d_in, const int* in_sizes, int n_in,
                              void* d_out, int out_size, void* d_ws, size_t ws_size,
                              hipStream_t stream) {
  const float* enc = (const float*)d_in[0];
  const float* wih = (const float*)d_in[1];
  const float* whh = (const float*)d_in[2];
  const float* bih = (const float*)d_in[3];
  const float* bhh = (const float*)d_in[4];
  float* outp = (float*)d_out;
  unsigned char* ws = (unsigned char*)d_ws;

  hipLaunchKernelGGL(init_ws, dim3(64), dim3(256), 0, stream, (unsigned int*)ws);

  hipFuncSetAttribute((const void*)decoder_main,
                      hipFuncAttributeMaxDynamicSharedMemorySize, SMEM_BYTES);

  void* args[] = { (void*)&enc, (void*)&wih, (void*)&whh, (void*)&bih,
                   (void*)&bhh, (void*)&outp, (void*)&ws };
  hipLaunchCooperativeKernel((void*)decoder_main, dim3(NBLK), dim3(NTHR),
                             args, SMEM_BYTES, stream);
}

// Round 4
// 4161.522 us; speedup vs baseline: 7.1368x; 1.3604x over previous
//
#include <hip/hip_runtime.h>
#include <math.h>

#define Bq   32
#define Sq   1024
#define Hq   256

#define NBLK 256
#define NTHR 512
#define GRP  16     // blocks per group (group owns 2 batch rows)

// --- workspace layout (bytes) ---
#define WS_CNT   0        // 16 group counters, 128-B spacing (final barrier only)
#define WS_WIN   2048     // u64 win[16][2][16]: per (group, batch, r) tagged slice-winner
#define WS_HBUF  6144     // u64 hbuf[32][256]: tagged h (hi32 = t+1, lo32 = f32 bits)
#define WS_TOTAL 71680

// --- LDS layout (float offsets) --- (~9.4 KB used; SMEM padded to pin 1 blk/CU)
#define L_VH     0        // [2][256]  h_prev vectors (stashed by phase B)
#define L_SCR    512      // [128][9]  gemv partials: (mat*64+l64)*9 + q*2 + b
#define L_GVL    1664     // [2][64]   gate values
#define L_BIAS   1792     // [64]      b_ih+b_hh, flattened kl*4+gate
#define L_C      1856     // [2][16]   cell state (persistent)
#define L_SCRB   1888     // [8][64]   score partials
#define SMEM_BYTES (84*1024)   // > 160K/2: pins exactly 1 block per CU

__global__ void init_ws(unsigned int* ws) {
  int n = WS_TOTAL / 4;
  for (int i = threadIdx.x + blockIdx.x * blockDim.x; i < n; i += blockDim.x * gridDim.x)
    ws[i] = 0u;
}

// Counter barrier — used ONCE (before deferred softmax). Loop is barrier-free.
__device__ __forceinline__ void group_barrier(unsigned int* mycnt) {
  asm volatile("s_waitcnt vmcnt(0)" ::: "memory");
  __syncthreads();
  if (threadIdx.x == 0) {
    unsigned int old = __hip_atomic_fetch_add(mycnt, 1u, __ATOMIC_RELAXED, __HIP_MEMORY_SCOPE_AGENT);
    unsigned int tgt = (old / GRP + 1u) * GRP;
    while (__hip_atomic_load(mycnt, __ATOMIC_RELAXED, __HIP_MEMORY_SCOPE_AGENT) < tgt) {}
  }
  __syncthreads();
}

__global__ void __launch_bounds__(NTHR, 2)
decoder_main(const float* __restrict__ enc, const float* __restrict__ wih,
             const float* __restrict__ whh, const float* __restrict__ bih,
             const float* __restrict__ bhh, float* __restrict__ out,
             unsigned char* wsb)
{
  extern __shared__ float sm[];
  unsigned int* cnt = (unsigned int*)(wsb + WS_CNT);
  unsigned long long* win  = (unsigned long long*)(wsb + WS_WIN);
  unsigned long long* hbuf = (unsigned long long*)(wsb + WS_HBUF);

  const int tid = threadIdx.x;
  const int grp = blockIdx.x & 15;
  const int r   = blockIdx.x >> 4;   // rank within group, 0..15
  const int b0  = grp * 2;
  unsigned int* mycnt = cnt + grp * 32;
  unsigned long long* gwin = win + grp * 32;   // [b*16 + r]

  const int wid = tid >> 6, lane = tid & 63;
  // phase-A roles: wave -> (mat, col-quarter); lane -> W row l64 = kl*4+gate
  const int amat = wid >> 2, aq = wid & 3;
  const int kl_a = lane >> 2, gate_a = lane & 3;
  // phase-B roles: wave -> (batch-local, col-quarter); lane -> s_local
  const int bbl = wid >> 2, bjc = wid & 3;

  // ---------------- init: W slice -> registers (64 floats/thread) ----------------
  float wreg[64];
  {
    const float* wsrc = (amat ? whh : wih)
                      + ((size_t)(gate_a * Hq + r * 16 + kl_a)) * Hq + aq * 64;
    #pragma unroll
    for (int u = 0; u < 16; ++u) {
      float4 v = *(const float4*)(wsrc + u * 4);
      wreg[u * 4 + 0] = v.x; wreg[u * 4 + 1] = v.y;
      wreg[u * 4 + 2] = v.z; wreg[u * 4 + 3] = v.w;
    }
  }
  // ---------------- init: enc slice -> registers ----------------
  float er[64];
  {
    const float* ep = enc + ((size_t)(b0 + bbl) * Sq + (size_t)(r * 64 + lane)) * Hq + bjc * 64;
    #pragma unroll
    for (int u = 0; u < 16; ++u) {
      float4 v = *(const float4*)(ep + u * 4);
      er[u * 4 + 0] = v.x; er[u * 4 + 1] = v.y;
      er[u * 4 + 2] = v.z; er[u * 4 + 3] = v.w;
    }
  }
  // ---------------- init: LDS ----------------
  for (int i = tid; i < 512; i += NTHR) sm[L_VH + i] = 0.f;
  if (tid < 64) {
    int gr = gate_a * Hq + r * 16 + kl_a;  // tid<64 -> lane==tid
    sm[L_BIAS + tid] = bih[gr] + bhh[gr];
  }
  if (tid < 32) sm[L_C + tid] = 0.f;
  __syncthreads();

  // ================= main recurrence (barrier-free: tagged dataflow) =============
  for (int t = 0; t < Sq; ++t) {
    // --- phase A: dual GEMV. waves 4-7: W_hh·h from LDS (no external dep);
    //     waves 0-3: spin on winner tags, reduce global argmax in-wave,
    //     gather x directly from enc, W_ih·x. Spin overlaps the h-GEMV. ---
    float a0 = 0.f, a1 = 0.f;
    if (amat == 0) {
      if (t > 0) {
        unsigned long long w;
        {
          const unsigned long long* wp = gwin + (lane & 31);
          do {
            w = __hip_atomic_load(wp, __ATOMIC_RELAXED, __HIP_MEMORY_SCOPE_AGENT);
          } while ((unsigned int)(w >> 48) != (unsigned int)t);
        }
        #pragma unroll
        for (int off = 1; off < 16; off <<= 1) {   // max over 16 r-slices (within b-group)
          unsigned long long o = __shfl_xor(w, off);
          if (o > w) w = o;
        }
        unsigned long long wo = __shfl_xor(w, 16); // other batch's winner
        unsigned long long w0 = ((lane >> 4) & 1) ? wo : w;
        unsigned long long w1 = ((lane >> 4) & 1) ? w : wo;
        int ix0 = 1023 - (int)(w0 & 0xFFFF);
        int ix1 = 1023 - (int)(w1 & 0xFFFF);
        int vb0 = __float_as_int(enc[((size_t)(b0 + 0) * Sq + (size_t)ix0) * Hq + aq * 64 + lane]);
        int vb1 = __float_as_int(enc[((size_t)(b0 + 1) * Sq + (size_t)ix1) * Hq + aq * 64 + lane]);
        #pragma unroll
        for (int u = 0; u < 64; ++u) {
          float s0 = __int_as_float(__builtin_amdgcn_readlane(vb0, u));
          float s1 = __int_as_float(__builtin_amdgcn_readlane(vb1, u));
          a0 = fmaf(wreg[u], s0, a0);
          a1 = fmaf(wreg[u], s1, a1);
        }
      }
      // t==0: x = 0 -> partials stay 0
    } else {
      int vb0 = __float_as_int(sm[L_VH + aq * 64 + lane]);
      int vb1 = __float_as_int(sm[L_VH + 256 + aq * 64 + lane]);
      #pragma unroll
      for (int u = 0; u < 64; ++u) {
        float s0 = __int_as_float(__builtin_amdgcn_readlane(vb0, u));
        float s1 = __int_as_float(__builtin_amdgcn_readlane(vb1, u));
        a0 = fmaf(wreg[u], s0, a0);
        a1 = fmaf(wreg[u], s1, a1);
      }
    }
    sm[L_SCR + (amat * 64 + lane) * 9 + aq * 2 + 0] = a0;
    sm[L_SCR + (amat * 64 + lane) * 9 + aq * 2 + 1] = a1;
    __syncthreads();                                        // S1

    if (tid < 128) {   // combine quarters + ih/hh + bias -> gates
      int b = tid >> 6, l64 = tid & 63;
      float s = sm[L_BIAS + l64];
      #pragma unroll
      for (int q = 0; q < 4; ++q) s += sm[L_SCR + l64 * 9 + q * 2 + b];
      #pragma unroll
      for (int q = 0; q < 4; ++q) s += sm[L_SCR + (64 + l64) * 9 + q * 2 + b];
      sm[L_GVL + b * 64 + l64] = s;
    }
    __syncthreads();                                        // S2

    if (tid < 32) {    // LSTM cell update; publish tagged h
      int b = tid >> 4, kl = tid & 15;
      float g0 = sm[L_GVL + b * 64 + kl * 4 + 0];
      float g1 = sm[L_GVL + b * 64 + kl * 4 + 1];
      float g2 = sm[L_GVL + b * 64 + kl * 4 + 2];
      float g3 = sm[L_GVL + b * 64 + kl * 4 + 3];
      float gi = 1.f / (1.f + expf(-g0));
      float gf = 1.f / (1.f + expf(-g1));
      float gg = tanhf(g2);
      float go = 1.f / (1.f + expf(-g3));
      float c = gf * sm[L_C + b * 16 + kl] + gi * gg;
      sm[L_C + b * 16 + kl] = c;
      float h = go * tanhf(c);
      unsigned long long hw = ((unsigned long long)(unsigned int)(t + 1) << 32)
                            | (unsigned long long)__float_as_uint(h);
      __hip_atomic_store(&hbuf[(size_t)(b0 + b) * Hq + r * 16 + kl], hw,
                         __ATOMIC_RELAXED, __HIP_MEMORY_SCOPE_AGENT);
    }

    // --- phase B: spin on tagged h word, stash to LDS, score FMA ---
    {
      unsigned long long hw;
      {
        const unsigned long long* hp = &hbuf[(size_t)(b0 + bbl) * Hq + bjc * 64 + lane];
        do {
          hw = __hip_atomic_load(hp, __ATOMIC_RELAXED, __HIP_MEMORY_SCOPE_AGENT);
        } while ((unsigned int)(hw >> 32) != (unsigned int)(t + 1));
      }
      float hval = __uint_as_float((unsigned int)hw);
      sm[L_VH + bbl * 256 + bjc * 64 + lane] = hval;   // for next step's h-GEMV
      int hbits = __float_as_int(hval);
      float p0 = 0.f, p1 = 0.f, p2 = 0.f, p3 = 0.f;
      #pragma unroll
      for (int u = 0; u < 64; u += 4) {
        p0 = fmaf(er[u + 0], __int_as_float(__builtin_amdgcn_readlane(hbits, u + 0)), p0);
        p1 = fmaf(er[u + 1], __int_as_float(__builtin_amdgcn_readlane(hbits, u + 1)), p1);
        p2 = fmaf(er[u + 2], __int_as_float(__builtin_amdgcn_readlane(hbits, u + 2)), p2);
        p3 = fmaf(er[u + 3], __int_as_float(__builtin_amdgcn_readlane(hbits, u + 3)), p3);
      }
      float ps = (p0 + p1) + (p2 + p3);
      sm[L_SCRB + wid * 64 + lane] = ps;
    }
    __syncthreads();                                        // S3

    if (tid < 128) {   // final scores; out store; slice-winner publish (tagged)
      int b = tid >> 6, sl = tid & 63;
      const float* q = &sm[L_SCRB + b * 256 + sl];
      float sc = (q[0] + q[64]) + (q[128] + q[192]);
      out[((size_t)(b0 + b) * Sq + (size_t)t) * Sq + r * 64 + sl] = sc;
      unsigned int kb = __float_as_uint(sc);
      kb = (kb & 0x80000000u) ? ~kb : (kb | 0x80000000u);   // sortable key
      unsigned long long pk = ((unsigned long long)(unsigned int)(t + 1) << 48)
                            | ((unsigned long long)kb << 16)
                            | (unsigned long long)(1023 - (r * 64 + sl)); // tie -> lowest s
      #pragma unroll
      for (int off = 32; off > 0; off >>= 1) {
        unsigned long long o = __shfl_down(pk, off);
        if (o > pk) pk = o;
      }
      if (sl == 0)
        __hip_atomic_store(&gwin[b * 16 + r], pk,
                           __ATOMIC_RELAXED, __HIP_MEMORY_SCOPE_AGENT);
    }
    __syncthreads();                                        // S4 (SCRB/VH reuse)
  }

  // One-time flush+inv of cached score lines; single counter barrier; then
  // peers' rows are at the coherence point and our caches hold nothing stale.
  __threadfence();
  group_barrier(mycnt);

  // ================= deferred softmax: one row per wave, no syncs =================
  {
    const int gw = r * 8 + wid;   // wave id within group, 0..127
    #pragma unroll 1
    for (int u = 0; u < 16; ++u) {
      int lr = u * 128 + gw;            // local row 0..2047
      int b = lr >> 10, tt = lr & 1023;
      float* rowp = out + ((size_t)(b0 + b) * Sq + (size_t)tt) * Sq;
      float4 x0 = *(const float4*)(rowp + lane * 16 + 0);
      float4 x1 = *(const float4*)(rowp + lane * 16 + 4);
      float4 x2 = *(const float4*)(rowp + lane * 16 + 8);
      float4 x3 = *(const float4*)(rowp + lane * 16 + 12);
      float m = fmaxf(fmaxf(fmaxf(x0.x, x0.y), fmaxf(x0.z, x0.w)),
                      fmaxf(fmaxf(x1.x, x1.y), fmaxf(x1.z, x1.w)));
      m = fmaxf(m, fmaxf(fmaxf(fmaxf(x2.x, x2.y), fmaxf(x2.z, x2.w)),
                         fmaxf(fmaxf(x3.x, x3.y), fmaxf(x3.z, x3.w))));
      #pragma unroll
      for (int off = 32; off; off >>= 1) m = fmaxf(m, __shfl_xor(m, off));
      x0.x = __expf(x0.x - m); x0.y = __expf(x0.y - m); x0.z = __expf(x0.z - m); x0.w = __expf(x0.w - m);
      x1.x = __expf(x1.x - m); x1.y = __expf(x1.y - m); x1.z = __expf(x1.z - m); x1.w = __expf(x1.w - m);
      x2.x = __expf(x2.x - m); x2.y = __expf(x2.y - m); x2.z = __expf(x2.z - m); x2.w = __expf(x2.w - m);
      x3.x = __expf(x3.x - m); x3.y = __expf(x3.y - m); x3.z = __expf(x3.z - m); x3.w = __expf(x3.w - m);
      float s = ((x0.x + x0.y) + (x0.z + x0.w)) + ((x1.x + x1.y) + (x1.z + x1.w))
              + ((x2.x + x2.y) + (x2.z + x2.w)) + ((x3.x + x3.y) + (x3.z + x3.w));
      #pragma unroll
      for (int off = 32; off; off >>= 1) s += __shfl_xor(s, off);
      float inv = 1.f / s;
      x0.x *= inv; x0.y *= inv; x0.z *= inv; x0.w *= inv;
      x1.x *= inv; x1.y *= inv; x1.z *= inv; x1.w *= inv;
      x2.x *= inv; x2.y *= inv; x2.z *= inv; x2.w *= inv;
      x3.x *= inv; x3.y *= inv; x3.z *= inv; x3.w *= inv;
      *(float4*)(rowp + lane * 16 + 0)  = x0;
      *(float4*)(rowp + lane * 16 + 4)  = x1;
      *(float4*)(rowp + lane * 16 + 8)  = x2;
      *(float4*)(rowp + lane * 16 + 12) = x3;
    }
  }
}

extern "C" void kernel_launch(void* const* d_in, const int* in_sizes, int n_in,
                              void* d_out, int out_size, void* d_ws, size_t ws_size,
                              hipStream_t stream) {
  const float* enc = (const float*)d_in[0];
  const float* wih = (const float*)d_in[1];
  const float* whh = (const float*)d_in[2];
  const float* bih = (const float*)d_in[3];
  const float* bhh = (const float*)d_in[4];
  float* outp = (float*)d_out;
  unsigned char* ws = (unsigned char*)d_ws;

  hipLaunchKernelGGL(init_ws, dim3(64), dim3(256), 0, stream, (unsigned int*)ws);

  hipFuncSetAttribute((const void*)decoder_main,
                      hipFuncAttributeMaxDynamicSharedMemorySize, SMEM_BYTES);

  void* args[] = { (void*)&enc, (void*)&wih, (void*)&whh, (void*)&bih,
                   (void*)&bhh, (void*)&outp, (void*)&ws };
  hipLaunchCooperativeKernel((void*)decoder_main, dim3(NBLK), dim3(NTHR),
                             args, SMEM_BYTES, stream);
}